// Round 1
// baseline (1330.858 us; speedup 1.0000x reference)
//
#include <hip/hip_runtime.h>
#include <math.h>

#define BB 64
#define TT 4096
#define KSZ 1024
#define QSZ 1024

// ---------------------------------------------------------------------------
// Kernel A: mids[b,k] = dot(W[k,:], query[b,:])
// bid mapping: kt = bid>>6, b = bid&63  ->  consecutive blocks share the SAME
// 16 W rows (64 KB tile) so the tile is L2-hot across the 64 b's that reuse
// it; query (256 KB total) stays L2-resident. (Old mapping re-fetched W per b.)
// ---------------------------------------------------------------------------
__global__ __launch_bounds__(256) void mids_kernel(const float* __restrict__ query,
                                                   const float* __restrict__ W,
                                                   float* __restrict__ mids) {
    const int bid  = blockIdx.x;
    const int b    = bid & 63;   // 64 b's per W tile
    const int kt   = bid >> 6;   // k-tile of 16
    const int lane = threadIdx.x & 63;
    const int wave = threadIdx.x >> 6;

    const float4* q4 = (const float4*)(query + (size_t)b * QSZ);
    float4 qr[4];
#pragma unroll
    for (int c = 0; c < 4; ++c) qr[c] = q4[lane + c * 64];

#pragma unroll
    for (int i = 0; i < 4; ++i) {
        const int k = kt * 16 + wave * 4 + i;
        const float4* w4 = (const float4*)(W + (size_t)k * QSZ);
        float sum = 0.f;
#pragma unroll
        for (int c = 0; c < 4; ++c) {
            float4 wv = w4[lane + c * 64];
            sum += wv.x * qr[c].x + wv.y * qr[c].y + wv.z * qr[c].z + wv.w * qr[c].w;
        }
#pragma unroll
        for (int off = 32; off > 0; off >>= 1) sum += __shfl_xor(sum, off, 64);
        if (lane == 0) mids[b * KSZ + k] = sum;
    }
}

// ---------------------------------------------------------------------------
// Kernel B (fused scores + exp + mask): since tanh outputs are in [-1,1] and
// softmax is shift-invariant, exp(s - 1) gives an identical normalized result
// to exp(s - max) without needing the global max. Each block writes its 16
// e-values directly to out and one deterministic partial sum to ws.
// key streamed float4 (64 lanes x 16 B = 1 KB contiguous per instruction).
// ---------------------------------------------------------------------------
__global__ __launch_bounds__(256) void scores_kernel(const float* __restrict__ key,
                                                     const float* __restrict__ mids,
                                                     const float* __restrict__ mask,
                                                     const float* __restrict__ bias,
                                                     float* __restrict__ out,
                                                     float* __restrict__ partial) {
    const int bid  = blockIdx.x;
    const int b    = bid >> 8;   // 256 t-tiles per b
    const int tt   = bid & 255;  // t-tile of 16
    const int lane = threadIdx.x & 63;
    const int wave = threadIdx.x >> 6;
    __shared__ float red[4];

    const float4* m4 = (const float4*)(mids + (size_t)b * KSZ);
    float4 mr[4];
#pragma unroll
    for (int c = 0; c < 4; ++c) mr[c] = m4[lane + c * 64];
    const float bv = bias[0];

    float esum = 0.f;
#pragma unroll
    for (int i = 0; i < 4; ++i) {
        const int t = tt * 16 + wave * 4 + i;
        const float4* k4 = (const float4*)(key + ((size_t)b * TT + t) * KSZ);
        float sum = 0.f;
#pragma unroll
        for (int c = 0; c < 4; ++c) {
            float4 kv = k4[lane + c * 64];
            sum += kv.x * mr[c].x + kv.y * mr[c].y + kv.z * mr[c].z + kv.w * mr[c].w;
        }
#pragma unroll
        for (int off = 32; off > 0; off >>= 1) sum += __shfl_xor(sum, off, 64);
        if (lane == 0) {
            float e = expf(tanhf(sum + bv) - 1.0f) * mask[(size_t)b * TT + t];
            out[(size_t)b * TT + t] = e;
            esum += e;
        }
    }
    if (lane == 0) red[wave] = esum;
    __syncthreads();
    if (threadIdx.x == 0) partial[bid] = (red[0] + red[1]) + (red[2] + red[3]);
}

// ---------------------------------------------------------------------------
// Kernel C: per-b total from the 256 partials, then scale out in place.
// grid = BB blocks, 256 threads; 2 MB total traffic.
// ---------------------------------------------------------------------------
__global__ __launch_bounds__(256) void norm_kernel(const float* __restrict__ partial,
                                                   float* __restrict__ out) {
    const int b    = blockIdx.x;
    const int tid  = threadIdx.x;
    const int lane = tid & 63;
    const int wave = tid >> 6;
    __shared__ float red[4];

    float s = partial[b * 256 + tid];
#pragma unroll
    for (int off = 32; off > 0; off >>= 1) s += __shfl_xor(s, off, 64);
    if (lane == 0) red[wave] = s;
    __syncthreads();
    const float total = (red[0] + red[1]) + (red[2] + red[3]);
    const float inv = 1.0f / total;

    float4* o4 = (float4*)(out + (size_t)b * TT);
#pragma unroll
    for (int c = 0; c < 4; ++c) {
        float4 v = o4[tid + c * 256];
        v.x *= inv; v.y *= inv; v.z *= inv; v.w *= inv;
        o4[tid + c * 256] = v;
    }
}

extern "C" void kernel_launch(void* const* d_in, const int* in_sizes, int n_in,
                              void* d_out, int out_size, void* d_ws, size_t ws_size,
                              hipStream_t stream) {
    const float* query = (const float*)d_in[0];  // [64, 1024]
    const float* key   = (const float*)d_in[1];  // [64, 4096, 1024]
    const float* mask  = (const float*)d_in[2];  // [64, 4096]
    const float* W     = (const float*)d_in[3];  // [1024, 1024]
    const float* bias  = (const float*)d_in[4];  // [1]
    float* out = (float*)d_out;                  // [64, 4096]

    float* mids    = (float*)d_ws;               // 64*1024 floats = 256 KB
    float* partial = mids + BB * KSZ;            // 64*256 floats  =  64 KB

    mids_kernel<<<BB * (KSZ / 16), 256, 0, stream>>>(query, W, mids);
    scores_kernel<<<BB * (TT / 16), 256, 0, stream>>>(key, mids, mask, bias, out, partial);
    norm_kernel<<<BB, 256, 0, stream>>>(partial, out);
}